// Round 2
// baseline (1424.369 us; speedup 1.0000x reference)
//
#include <hip/hip_runtime.h>
#include <hip/hip_bf16.h>

#define BATCH 8192
#define NLAY  60
#define NX    4
#define NXS   3
#define NH    64
#define NMEM  16
#define NY    4
#define NYS   3
#define KX    80      // NH + NMEM (LSTM1 input width)
#define K1    144     // KX + NH
#define K2    128     // NH + NH
#define NG    256     // 4*NH gates
#define ROWS  16      // batch rows per block
#define TPB   256

typedef __hip_bfloat16 bf16;

__device__ __forceinline__ float b2f(bf16 v) { return __bfloat162float(v); }
__device__ __forceinline__ bf16  f2b(float v) { return __float2bfloat16(v); }
__device__ __forceinline__ float rcp_(float x) { return __builtin_amdgcn_rcpf(x); }
__device__ __forceinline__ float sigm_(float x) { return rcp_(1.0f + __expf(-x)); }
__device__ __forceinline__ float tanh_(float x) {
  x = fminf(fmaxf(x, -15.0f), 15.0f);
  float e = __expf(2.0f * x);
  return (e - 1.0f) * rcp_(e + 1.0f);
}

// Repack gate weights into ws, layout WT[k][j][gate] (gate fastest) so each
// lane j loads its 4 gate weights for step k as one float4.
__global__ void wtranspose(const float* __restrict__ Wih1, const float* __restrict__ Whh1,
                           const float* __restrict__ Wih2, const float* __restrict__ Whh2,
                           float* __restrict__ ws) {
  int idx = blockIdx.x * blockDim.x + threadIdx.x;
  if (idx < K1 * NG) {
    int k = idx / NG, rem = idx - k * NG;
    int j = rem >> 2, gate = rem & 3;
    int g = gate * NH + j;                       // PyTorch gate order i,f,g,o
    ws[idx] = (k < KX) ? Wih1[g * KX + k] : Whh1[g * NH + (k - KX)];
  } else if (idx < (K1 + K2) * NG) {
    int i2 = idx - K1 * NG;
    int k = i2 / NG, rem = i2 - k * NG;
    int j = rem >> 2, gate = rem & 3;
    int g = gate * NH + j;
    ws[K1 * NG + i2] = (k < NH) ? Wih2[g * NH + k] : Whh2[g * NH + (k - NH)];
  }
}

__global__ __launch_bounds__(TPB)
void lstm_fused(const float* __restrict__ inputs_main,  // [B,60,4]
                const float* __restrict__ inputs_aux,   // [B,3]
                const float* __restrict__ rnn1_mem,     // [B,60,16]
                const float* __restrict__ Wi,  const float* __restrict__ bi,
                const float* __restrict__ Ws1, const float* __restrict__ bs1,
                const float* __restrict__ Ws2, const float* __restrict__ bs2,
                const float* __restrict__ Wt1, const float* __restrict__ bt1,
                const float* __restrict__ Wt2, const float* __restrict__ bt2,
                const float* __restrict__ bih1, const float* __restrict__ bhh1,
                const float* __restrict__ bih2, const float* __restrict__ bhh2,
                const float* __restrict__ Wl,  const float* __restrict__ bl,
                const float* __restrict__ Wo,  const float* __restrict__ bo,
                const float* __restrict__ Wso, const float* __restrict__ bso,
                const float* __restrict__ WT1, const float* __restrict__ WT2,
                bf16* __restrict__ r1buf,              // [B,60,64] scratch (bf16)
                float* __restrict__ out, float* __restrict__ out_sfc,
                float* __restrict__ new_mem) {
  __shared__ float xh1[ROWS][K1 + 1];          // [0:80)=xcat, [80:144)=h1
  __shared__ float xh2[ROWS][K2 + 1];          // [0:64)=r1_t, [64:128)=h2
  __shared__ float latS[ROWS][NMEM + 1];
  __shared__ float WiS[NH * NX];
  __shared__ float biS[NH];
  __shared__ float WlS[NMEM][NH + 1];
  __shared__ float inmS[ROWS][NLAY * NX + 1];  // stride 241 breaks bank aliasing

  const int tid = threadIdx.x;
  const int j   = tid & 63;                    // gate column
  const int rg  = tid >> 6;                    // row group (wave id)
  const int b0  = blockIdx.x * ROWS;

  // ---- preload small weights + this block's inputs_main tile ----
  for (int e = tid; e < NH * NX; e += TPB) WiS[e] = Wi[e];
  if (tid < NH) biS[tid] = bi[tid];
  for (int e = tid; e < NMEM * NH; e += TPB) WlS[e >> 6][e & 63] = Wl[e];
  for (int e = tid; e < ROWS * NLAY * NX; e += TPB) {
    int r = e / (NLAY * NX), c = e - r * (NLAY * NX);
    inmS[r][c] = inputs_main[(size_t)(b0 + r) * (NLAY * NX) + c];
  }

  float bg1[4], bg2[4];
#pragma unroll
  for (int g = 0; g < 4; ++g) {
    bg1[g] = bih1[g * NH + j] + bhh1[g * NH + j];
    bg2[g] = bih2[g * NH + j] + bhh2[g * NH + j];
  }

  // ---- LSTM1 initial state: h = tanh(aux@Ws1^T+bs1), c = tanh(aux@Ws2^T+bs2)
  float c1[4];
  {
    float w10 = Ws1[j * 3 + 0], w11 = Ws1[j * 3 + 1], w12 = Ws1[j * 3 + 2];
    float w20 = Ws2[j * 3 + 0], w21 = Ws2[j * 3 + 1], w22 = Ws2[j * 3 + 2];
    float bb1 = bs1[j], bb2 = bs2[j];
#pragma unroll
    for (int rr = 0; rr < 4; ++rr) {
      int r = rg * 4 + rr;
      const float* ax = &inputs_aux[(size_t)(b0 + r) * NXS];
      float a0 = ax[0], a1 = ax[1], a2 = ax[2];
      xh1[r][KX + j] = tanh_(w10 * a0 + w11 * a1 + w12 * a2 + bb1);
      c1[rr]         = tanh_(w20 * a0 + w21 * a1 + w22 * a2 + bb2);
    }
  }
  __syncthreads();

  // ---- LSTM1: process original time t = 59..0 (flipped scan); r1[t] = h(t)
  for (int t = NLAY - 1; t >= 0; --t) {
    // Phase A: xcat = [tanh(inp@Wi^T+bi) | rnn1_mem]
    for (int e = tid; e < ROWS * NH; e += TPB) {
      int r = e & (ROWS - 1), col = e >> 4;
      const float* w  = &WiS[col * NX];
      const float* xm = &inmS[r][t * NX];
      xh1[r][col] = tanh_(biS[col] + w[0]*xm[0] + w[1]*xm[1] + w[2]*xm[2] + w[3]*xm[3]);
    }
    {
      int r = tid >> 4, m = tid & 15;
      xh1[r][NH + m] = rnn1_mem[((size_t)(b0 + r) * NLAY + t) * NMEM + m];
    }
    __syncthreads();
    // Phase B: gate pre-activations, 4 rows x 4 gates per thread
    float acc[4][4];
#pragma unroll
    for (int g = 0; g < 4; ++g)
#pragma unroll
      for (int rr = 0; rr < 4; ++rr) acc[g][rr] = bg1[g];
    const float4* Wp = reinterpret_cast<const float4*>(WT1) + j;
#pragma unroll 4
    for (int k = 0; k < K1; ++k) {
      float4 w = Wp[(size_t)k * 64];
      float x0 = xh1[rg * 4 + 0][k];
      float x1 = xh1[rg * 4 + 1][k];
      float x2 = xh1[rg * 4 + 2][k];
      float x3 = xh1[rg * 4 + 3][k];
      acc[0][0] += w.x * x0; acc[0][1] += w.x * x1; acc[0][2] += w.x * x2; acc[0][3] += w.x * x3;
      acc[1][0] += w.y * x0; acc[1][1] += w.y * x1; acc[1][2] += w.y * x2; acc[1][3] += w.y * x3;
      acc[2][0] += w.z * x0; acc[2][1] += w.z * x1; acc[2][2] += w.z * x2; acc[2][3] += w.z * x3;
      acc[3][0] += w.w * x0; acc[3][1] += w.w * x1; acc[3][2] += w.w * x2; acc[3][3] += w.w * x3;
    }
    __syncthreads();
    // Phase C: nonlinearity, state update, h -> LDS + r1 scratch
#pragma unroll
    for (int rr = 0; rr < 4; ++rr) {
      int r = rg * 4 + rr;
      float ig = sigm_(acc[0][rr]);
      float fg = sigm_(acc[1][rr]);
      float gg = tanh_(acc[2][rr]);
      float og = sigm_(acc[3][rr]);
      float c  = fg * c1[rr] + ig * gg;
      c1[rr] = c;
      float h = og * tanh_(c);
      xh1[r][KX + j] = h;
      r1buf[((size_t)(b0 + r) * NLAY + t) * NH + j] = f2b(h);
    }
  }
  __syncthreads();   // r1buf writes drained (barrier implies vmcnt(0))

  // ---- LSTM2 initial state: h = toa*Wt1+bt1, c = toa*Wt2+bt2 (no tanh)
  float c2[4];
  {
    float wt1 = Wt1[j], wt2 = Wt2[j];
    float bb1 = bt1[j], bb2 = bt2[j];
#pragma unroll
    for (int rr = 0; rr < 4; ++rr) {
      int r = rg * 4 + rr;
      float toa = inputs_aux[(size_t)(b0 + r) * NXS + 1];
      xh2[r][NH + j] = toa * wt1 + bb1;
      c2[rr]         = toa * wt2 + bb2;
    }
  }

  // ---- LSTM2: forward t = 0..59
  for (int t = 0; t < NLAY; ++t) {
    // A2: load r1[t]
    for (int e = tid; e < ROWS * NH; e += TPB) {
      int r = e >> 6, jj = e & 63;
      xh2[r][jj] = b2f(r1buf[((size_t)(b0 + r) * NLAY + t) * NH + jj]);
    }
    __syncthreads();
    // B2: gates
    float acc[4][4];
#pragma unroll
    for (int g = 0; g < 4; ++g)
#pragma unroll
      for (int rr = 0; rr < 4; ++rr) acc[g][rr] = bg2[g];
    const float4* Wp2 = reinterpret_cast<const float4*>(WT2) + j;
#pragma unroll 4
    for (int k = 0; k < K2; ++k) {
      float4 w = Wp2[(size_t)k * 64];
      float x0 = xh2[rg * 4 + 0][k];
      float x1 = xh2[rg * 4 + 1][k];
      float x2 = xh2[rg * 4 + 2][k];
      float x3 = xh2[rg * 4 + 3][k];
      acc[0][0] += w.x * x0; acc[0][1] += w.x * x1; acc[0][2] += w.x * x2; acc[0][3] += w.x * x3;
      acc[1][0] += w.y * x0; acc[1][1] += w.y * x1; acc[1][2] += w.y * x2; acc[1][3] += w.y * x3;
      acc[2][0] += w.z * x0; acc[2][1] += w.z * x1; acc[2][2] += w.z * x2; acc[2][3] += w.z * x3;
      acc[3][0] += w.w * x0; acc[3][1] += w.w * x1; acc[3][2] += w.w * x2; acc[3][3] += w.w * x3;
    }
    __syncthreads();
    // C2: state update
#pragma unroll
    for (int rr = 0; rr < 4; ++rr) {
      int r = rg * 4 + rr;
      float ig = sigm_(acc[0][rr]);
      float fg = sigm_(acc[1][rr]);
      float gg = tanh_(acc[2][rr]);
      float og = sigm_(acc[3][rr]);
      float c  = fg * c2[rr] + ig * gg;
      c2[rr] = c;
      xh2[r][NH + j] = og * tanh_(c);
    }
    __syncthreads();
    // D1: lat = h2 @ Wl^T + bl  -> latS, new_mem
    {
      int rl = tid >> 4, m = tid & 15;
      float a = bl[m];
#pragma unroll
      for (int k = 0; k < NH; ++k) a += xh2[rl][NH + k] * WlS[m][k];
      latS[rl][m] = a;
      new_mem[((size_t)(b0 + rl) * NLAY + t) * NMEM + m] = a;
    }
    __syncthreads();
    // D2: out = lat @ Wo^T + bo
    if (tid < ROWS * NY) {
      int rl = tid >> 2, y = tid & 3;
      float a = bo[y];
#pragma unroll
      for (int m = 0; m < NMEM; ++m) a += latS[rl][m] * Wo[y * NMEM + m];
      out[((size_t)(b0 + rl) * NLAY + t) * NY + y] = a;
    }
  }
  __syncthreads();
  // out_sfc = hL @ Wso^T + bso
  if (tid < ROWS * NYS) {
    int rl = tid / NYS, yy = tid - rl * NYS;
    float a = bso[yy];
#pragma unroll
    for (int k = 0; k < NH; ++k) a += xh2[rl][NH + k] * Wso[yy * NH + k];
    out_sfc[(size_t)(b0 + rl) * NYS + yy] = a;
  }
}

extern "C" void kernel_launch(void* const* d_in, const int* in_sizes, int n_in,
                              void* d_out, int out_size, void* d_ws, size_t ws_size,
                              hipStream_t stream) {
  (void)in_sizes; (void)n_in; (void)out_size; (void)ws_size;
  const float* inputs_main = (const float*)d_in[0];
  const float* inputs_aux  = (const float*)d_in[1];
  const float* rnn1_mem    = (const float*)d_in[2];
  const float* Wi   = (const float*)d_in[3];
  const float* bi   = (const float*)d_in[4];
  const float* Ws1  = (const float*)d_in[5];
  const float* bs1  = (const float*)d_in[6];
  const float* Ws2  = (const float*)d_in[7];
  const float* bs2  = (const float*)d_in[8];
  const float* Wt1  = (const float*)d_in[9];
  const float* bt1  = (const float*)d_in[10];
  const float* Wt2  = (const float*)d_in[11];
  const float* bt2  = (const float*)d_in[12];
  const float* Wih1 = (const float*)d_in[13];
  const float* Whh1 = (const float*)d_in[14];
  const float* bih1 = (const float*)d_in[15];
  const float* bhh1 = (const float*)d_in[16];
  const float* Wih2 = (const float*)d_in[17];
  const float* Whh2 = (const float*)d_in[18];
  const float* bih2 = (const float*)d_in[19];
  const float* bhh2 = (const float*)d_in[20];
  const float* Wl   = (const float*)d_in[21];
  const float* bl   = (const float*)d_in[22];
  const float* Wo   = (const float*)d_in[23];
  const float* bo   = (const float*)d_in[24];
  const float* Wso  = (const float*)d_in[25];
  const float* bso  = (const float*)d_in[26];

  float* out     = (float*)d_out;
  float* out_sfc = out + (size_t)BATCH * NLAY * NY;
  float* new_mem = out_sfc + (size_t)BATCH * NYS;

  float* ws  = (float*)d_ws;
  float* WT1 = ws;                                // [K1][64][4] fp32
  float* WT2 = ws + K1 * NG;                      // [K2][64][4] fp32
  bf16*  r1buf = (bf16*)(ws + (K1 + K2) * NG);    // [B][60][64] bf16, ~63 MB

  wtranspose<<<(K1 + K2) * NG / 256, 256, 0, stream>>>(Wih1, Whh1, Wih2, Whh2, ws);
  lstm_fused<<<BATCH / ROWS, TPB, 0, stream>>>(
      inputs_main, inputs_aux, rnn1_mem, Wi, bi, Ws1, bs1, Ws2, bs2,
      Wt1, bt1, Wt2, bt2, bih1, bhh1, bih2, bhh2, Wl, bl, Wo, bo, Wso, bso,
      WT1, WT2, r1buf, out, out_sfc, new_mem);
}

// Round 3
// 279.871 us; speedup vs baseline: 5.0894x; 5.0894x over previous
//
#include <hip/hip_runtime.h>
#include <hip/hip_bf16.h>

#define BATCH 8192
#define NLAY  60
#define NH    64
#define NMEM  16
#define ROWS  16
#define TPB   256
#define S1    168    // xh1 row stride (ushort): 84 dwords -> <=2-way bank aliasing
#define S2    136    // xh2 row stride (ushort): 68 dwords

typedef unsigned short ushort_t;
typedef __attribute__((ext_vector_type(8))) short short8;
typedef __attribute__((ext_vector_type(4))) short short4v;
typedef __attribute__((ext_vector_type(4))) float f32x4;
typedef __attribute__((ext_vector_type(4))) float f4v;

__device__ __forceinline__ float rcp_(float x) { return __builtin_amdgcn_rcpf(x); }
__device__ __forceinline__ float sigm_(float x) { return rcp_(1.0f + __expf(-x)); }
__device__ __forceinline__ float tanh_(float x) { return 1.0f - 2.0f * rcp_(__expf(2.0f * x) + 1.0f); }
__device__ __forceinline__ ushort_t f2bu(float f) {       // fp32 -> bf16 bits, RNE
  unsigned u = __float_as_uint(f);
  return (ushort_t)((u + 0x7FFFu + ((u >> 16) & 1u)) >> 16);
}
__device__ __forceinline__ float b2fu(ushort_t b) { return __uint_as_float(((unsigned)b) << 16); }

__device__ __forceinline__ f32x4 mfma16(short8 a, short8 b, f32x4 c) {
  return __builtin_amdgcn_mfma_f32_16x16x32_bf16(a, b, c, 0, 0, 0);
}

// ---- Pre-pass: repack gate weights into MFMA B-fragment order (bf16 bits) ----
// B-frag for 16x16x32: lane holds B[k=quad*8+j][n=lane&15], j=0..7 contiguous.
// W1f: [w][g][ks(5)][lane][8]  (40960) ; W2f: [w][g][ks(4)][lane][8] (32768) ;
// Wlf: [ks(2)][lane][8] (1024). Gate cols: gate g, unit u = w*16+(lane&15).
__global__ void wtranspose(const float* __restrict__ Wih1, const float* __restrict__ Whh1,
                           const float* __restrict__ Wih2, const float* __restrict__ Whh2,
                           const float* __restrict__ Wl, ushort_t* __restrict__ frag) {
  int e = blockIdx.x * 256 + threadIdx.x;
  float v;
  if (e < 40960) {
    int j = e & 7, lx = (e >> 3) & 63, rest = e >> 9;
    int ks = rest % 5, gw = rest / 5;
    int g = gw & 3, wv = gw >> 2;
    int uu = wv * 16 + (lx & 15);
    int k = ks * 32 + (lx >> 4) * 8 + j;
    int row = g * 64 + uu;
    v = (k < 80) ? Wih1[row * 80 + k] : (k < 144 ? Whh1[row * 64 + (k - 80)] : 0.0f);
  } else if (e < 73728) {
    int e2 = e - 40960;
    int j = e2 & 7, lx = (e2 >> 3) & 63, rest = e2 >> 9;
    int ks = rest & 3, g = (rest >> 2) & 3, wv = rest >> 4;
    int uu = wv * 16 + (lx & 15);
    int k = ks * 32 + (lx >> 4) * 8 + j;
    int row = g * 64 + uu;
    v = (k < 64) ? Wih2[row * 64 + k] : Whh2[row * 64 + (k - 64)];
  } else {
    int e3 = e - 73728;
    int j = e3 & 7, lx = (e3 >> 3) & 63, ks = e3 >> 9;
    int m = lx & 15, k = ks * 32 + (lx >> 4) * 8 + j;
    v = Wl[m * 64 + k];
  }
  frag[e] = f2bu(v);
}

// ---- Main persistent LSTM kernel: 512 blocks x 256 thr, 16 batch rows each ----
__global__ __launch_bounds__(TPB, 2)
void lstm_fused(const float* __restrict__ inputs_main, const float* __restrict__ inputs_aux,
                const float* __restrict__ rnn1_mem,
                const float* __restrict__ Wi,  const float* __restrict__ bi,
                const float* __restrict__ Ws1, const float* __restrict__ bs1,
                const float* __restrict__ Ws2, const float* __restrict__ bs2,
                const float* __restrict__ Wt1, const float* __restrict__ bt1,
                const float* __restrict__ Wt2, const float* __restrict__ bt2,
                const float* __restrict__ bih1, const float* __restrict__ bhh1,
                const float* __restrict__ bih2, const float* __restrict__ bhh2,
                const float* __restrict__ bl,
                const ushort_t* __restrict__ W1f, const ushort_t* __restrict__ W2f,
                const ushort_t* __restrict__ Wlf_g,
                ushort_t* __restrict__ r1buf, ushort_t* __restrict__ hLbuf,
                float* __restrict__ new_mem) {
  __shared__ __align__(16) ushort_t xh1[16 * S1];   // cols: x 0..63 | mem 64..79 | h 80..143 | pad 144..159
  __shared__ __align__(16) ushort_t xh2[16 * S2];   // cols: r1 0..63 | h2 64..127
  __shared__ __align__(16) float inmS[16][244];

  const int tid = threadIdx.x;
  const int l  = tid & 63, w = tid >> 6;
  const int ln = l & 15,  lq = l >> 4;
  const int u  = w * 16 + ln;              // this lane's hidden-unit column
  const int rowbase = lq * 4;              // C-layout rows: rowbase..rowbase+3
  const int b0 = blockIdx.x * ROWS;
  const int xr = tid >> 4, xm = tid & 15, xc0 = xm * 4;
  const int rr8 = tid >> 3, ch8 = tid & 7;

  // B1 fragments (weights resident in VGPRs through LSTM1 loop)
  short8 B1f[4][5];
#pragma unroll
  for (int g = 0; g < 4; ++g)
#pragma unroll
    for (int ks = 0; ks < 5; ++ks)
      B1f[g][ks] = *(const short8*)(W1f + (((w * 4 + g) * 5 + ks) << 9) + (l << 3));

  // x-generator weights (per-thread: 4 cols x 4 inputs)
  f4v wif[4];
#pragma unroll
  for (int cc = 0; cc < 4; ++cc) wif[cc] = *(const f4v*)(Wi + (xc0 + cc) * 4);
  f4v bifv = *(const f4v*)(bi + xc0);

  float bg1[4];
#pragma unroll
  for (int g = 0; g < 4; ++g) bg1[g] = bih1[g * 64 + u] + bhh1[g * 64 + u];

  // inputs_main tile -> LDS (fp32), zero the K-pad region
  for (int e = tid; e < 16 * 240; e += TPB) {
    int r = e / 240, c = e - r * 240;
    inmS[r][c] = inputs_main[(size_t)(b0 + r) * 240 + c];
  }
  if (tid < 192) {
    int r = tid / 12, cc2 = (tid - r * 12) * 2 + 144;
    xh1[r * S1 + cc2] = 0; xh1[r * S1 + cc2 + 1] = 0;
  }
  __syncthreads();

  // ---- prologue t=59: x(59), mem(59), h1/c1 init ----
  float c1[4];
  {
    float mv = rnn1_mem[(size_t)(b0 + xr) * 960 + 59 * 16 + xm];
    xh1[xr * S1 + 64 + xm] = f2bu(mv);
    f4v xin = *(const f4v*)&inmS[xr][59 * 4];
    short4v xpv;
#pragma unroll
    for (int cc = 0; cc < 4; ++cc) {
      float a = bifv[cc] + wif[cc][0] * xin[0] + wif[cc][1] * xin[1] + wif[cc][2] * xin[2] + wif[cc][3] * xin[3];
      xpv[cc] = (short)f2bu(tanh_(a));
    }
    *(short4v*)&xh1[xr * S1 + xc0] = xpv;

    float w10 = Ws1[u * 3 + 0], w11 = Ws1[u * 3 + 1], w12 = Ws1[u * 3 + 2], bb1 = bs1[u];
    float w20 = Ws2[u * 3 + 0], w21 = Ws2[u * 3 + 1], w22 = Ws2[u * 3 + 2], bb2 = bs2[u];
#pragma unroll
    for (int reg = 0; reg < 4; ++reg) {
      int row = rowbase + reg;
      const float* ax = inputs_aux + (size_t)(b0 + row) * 3;
      float a0 = ax[0], a1 = ax[1], a2 = ax[2];
      xh1[row * S1 + 80 + u] = f2bu(tanh_(w10 * a0 + w11 * a1 + w12 * a2 + bb1));
      c1[reg] = tanh_(w20 * a0 + w21 * a1 + w22 * a2 + bb2);
    }
  }
  __syncthreads();

  // ---- LSTM1: t = 59..0 (flipped scan) ----
  for (int t = NLAY - 1; t >= 0; --t) {
    float mv = 0.0f; f4v xin = {};
    if (t > 0) {
      mv  = rnn1_mem[(size_t)(b0 + xr) * 960 + (t - 1) * 16 + xm];
      xin = *(const f4v*)&inmS[xr][(t - 1) * 4];
    }
    short8 af[5];
#pragma unroll
    for (int ks = 0; ks < 5; ++ks)
      af[ks] = *(const short8*)&xh1[ln * S1 + ks * 32 + lq * 8];
    short4v hv = {};
    if (t < 59) hv = *(const short4v*)&xh1[xr * S1 + 80 + xc0];

    f32x4 acc[4];
#pragma unroll
    for (int g = 0; g < 4; ++g) acc[g] = (f32x4){bg1[g], bg1[g], bg1[g], bg1[g]};
#pragma unroll
    for (int ks = 0; ks < 5; ++ks)
#pragma unroll
      for (int g = 0; g < 4; ++g) acc[g] = mfma16(af[ks], B1f[g][ks], acc[g]);

    if (t < 59)
      *(short4v*)(r1buf + ((size_t)(b0 + xr) * 60 + (t + 1)) * 64 + xc0) = hv;

    short4v xpv = {};
    if (t > 0) {
#pragma unroll
      for (int cc = 0; cc < 4; ++cc) {
        float a = bifv[cc] + wif[cc][0] * xin[0] + wif[cc][1] * xin[1] + wif[cc][2] * xin[2] + wif[cc][3] * xin[3];
        xpv[cc] = (short)f2bu(tanh_(a));
      }
    }
    ushort_t hu[4];
#pragma unroll
    for (int reg = 0; reg < 4; ++reg) {
      float ig = sigm_(acc[0][reg]);
      float fg = sigm_(acc[1][reg]);
      float gg = tanh_(acc[2][reg]);
      float og = sigm_(acc[3][reg]);
      float c  = fg * c1[reg] + ig * gg;
      c1[reg] = c;
      hu[reg] = f2bu(og * tanh_(c));
    }
    __syncthreads();
#pragma unroll
    for (int reg = 0; reg < 4; ++reg) xh1[(rowbase + reg) * S1 + 80 + u] = hu[reg];
    if (t > 0) {
      *(short4v*)&xh1[xr * S1 + xc0] = xpv;
      xh1[xr * S1 + 64 + xm] = f2bu(mv);
    }
    __syncthreads();
  }

  // ---- transition: store r1(0); seed xh2; LSTM2 init; load B2/Wl frags ----
  float c2[4], bg2[4], blv;
  short8 B2f[4][4], Wlf[2];
  {
    short4v hv = *(const short4v*)&xh1[xr * S1 + 80 + xc0];
    *(short4v*)(r1buf + ((size_t)(b0 + xr) * 60 + 0) * 64 + xc0) = hv;
    *(short4v*)&xh2[xr * S2 + xc0] = hv;

    float wt1u = Wt1[u], wt2u = Wt2[u], bt1u = bt1[u], bt2u = bt2[u];
#pragma unroll
    for (int reg = 0; reg < 4; ++reg) {
      int row = rowbase + reg;
      float toa = inputs_aux[(size_t)(b0 + row) * 3 + 1];
      xh2[row * S2 + 64 + u] = f2bu(toa * wt1u + bt1u);
      c2[reg] = toa * wt2u + bt2u;
    }
#pragma unroll
    for (int g = 0; g < 4; ++g) bg2[g] = bih2[g * 64 + u] + bhh2[g * 64 + u];
#pragma unroll
    for (int g = 0; g < 4; ++g)
#pragma unroll
      for (int ks = 0; ks < 4; ++ks)
        B2f[g][ks] = *(const short8*)(W2f + (((w * 4 + g) * 4 + ks) << 9) + (l << 3));
    Wlf[0] = *(const short8*)(Wlf_g + (l << 3));
    Wlf[1] = *(const short8*)(Wlf_g + 512 + (l << 3));
    blv = bl[ln];
  }
  __syncthreads();

  // ---- LSTM2: t = 0..59 ----
  for (int t = 0; t < NLAY; ++t) {
    short8 r1v = {};
    if (t < 59 && tid < 128)
      r1v = *(const short8*)(r1buf + ((size_t)(b0 + rr8) * 60 + (t + 1)) * 64 + ch8 * 8);
    short8 af2[4];
#pragma unroll
    for (int ks = 0; ks < 4; ++ks)
      af2[ks] = *(const short8*)&xh2[ln * S2 + ks * 32 + lq * 8];

    f32x4 acc[4];
#pragma unroll
    for (int g = 0; g < 4; ++g) acc[g] = (f32x4){bg2[g], bg2[g], bg2[g], bg2[g]};
#pragma unroll
    for (int ks = 0; ks < 4; ++ks)
#pragma unroll
      for (int g = 0; g < 4; ++g) acc[g] = mfma16(af2[ks], B2f[g][ks], acc[g]);

    ushort_t h2u[4];
#pragma unroll
    for (int reg = 0; reg < 4; ++reg) {
      float ig = sigm_(acc[0][reg]);
      float fg = sigm_(acc[1][reg]);
      float gg = tanh_(acc[2][reg]);
      float og = sigm_(acc[3][reg]);
      float c  = fg * c2[reg] + ig * gg;
      c2[reg] = c;
      h2u[reg] = f2bu(og * tanh_(c));
    }
    __syncthreads();
#pragma unroll
    for (int reg = 0; reg < 4; ++reg) xh2[(rowbase + reg) * S2 + 64 + u] = h2u[reg];
    if (t < 59 && tid < 128)
      *(short8*)&xh2[rr8 * S2 + ch8 * 8] = r1v;
    __syncthreads();

    if (w == 0) {  // lat = h2 @ Wl^T + bl -> new_mem, via 2 MFMAs on wave 0
      short8 afL0 = *(const short8*)&xh2[ln * S2 + 64 + lq * 8];
      short8 afL1 = *(const short8*)&xh2[ln * S2 + 64 + 32 + lq * 8];
      f32x4 accL = (f32x4){blv, blv, blv, blv};
      accL = mfma16(afL0, Wlf[0], accL);
      accL = mfma16(afL1, Wlf[1], accL);
#pragma unroll
      for (int reg = 0; reg < 4; ++reg)
        new_mem[((size_t)(b0 + rowbase + reg) * 60 + t) * 16 + ln] = accL[reg];
    }
  }

  // ---- hL (h2 at t=59) -> hLbuf for the out_sfc post-pass ----
  {
    short4v hv = *(const short4v*)&xh2[xr * S2 + 64 + xc0];
    *(short4v*)(hLbuf + (size_t)(b0 + xr) * 64 + xc0) = hv;
  }
}

// ---- Post-pass: out = new_mem @ Wo^T + bo ; out_sfc = hL @ Wso^T + bso ----
__global__ void postpass(const float* __restrict__ new_mem, const ushort_t* __restrict__ hLbuf,
                         const float* __restrict__ Wo, const float* __restrict__ bo,
                         const float* __restrict__ Wso, const float* __restrict__ bso,
                         float* __restrict__ out, float* __restrict__ out_sfc) {
  int idx = blockIdx.x * 256 + threadIdx.x;          // 0 .. B*60-1
  int b = idx / 60, t = idx - b * 60;
  f4v nm[4];
#pragma unroll
  for (int i = 0; i < 4; ++i) nm[i] = *(const f4v*)(new_mem + (size_t)idx * 16 + i * 4);
  f4v ov;
#pragma unroll
  for (int y = 0; y < 4; ++y) {
    float a = bo[y];
#pragma unroll
    for (int m = 0; m < 16; ++m) a += nm[m >> 2][m & 3] * Wo[y * 16 + m];
    ov[y] = a;
  }
  *(f4v*)(out + (size_t)idx * 4) = ov;

  if (t == 59) {
    const ushort_t* hp = hLbuf + (size_t)b * 64;
    float s0 = bso[0], s1 = bso[1], s2 = bso[2];
#pragma unroll
    for (int kk = 0; kk < 8; ++kk) {
      short8 v = *(const short8*)(hp + kk * 8);
#pragma unroll
      for (int j = 0; j < 8; ++j) {
        float h = b2fu((ushort_t)v[j]);
        int k = kk * 8 + j;
        s0 += h * Wso[0 * 64 + k];
        s1 += h * Wso[1 * 64 + k];
        s2 += h * Wso[2 * 64 + k];
      }
    }
    out_sfc[(size_t)b * 3 + 0] = s0;
    out_sfc[(size_t)b * 3 + 1] = s1;
    out_sfc[(size_t)b * 3 + 2] = s2;
  }
}

extern "C" void kernel_launch(void* const* d_in, const int* in_sizes, int n_in,
                              void* d_out, int out_size, void* d_ws, size_t ws_size,
                              hipStream_t stream) {
  (void)in_sizes; (void)n_in; (void)out_size; (void)ws_size;
  const float* inputs_main = (const float*)d_in[0];
  const float* inputs_aux  = (const float*)d_in[1];
  const float* rnn1_mem    = (const float*)d_in[2];
  const float* Wi   = (const float*)d_in[3];
  const float* bi   = (const float*)d_in[4];
  const float* Ws1  = (const float*)d_in[5];
  const float* bs1  = (const float*)d_in[6];
  const float* Ws2  = (const float*)d_in[7];
  const float* bs2  = (const float*)d_in[8];
  const float* Wt1  = (const float*)d_in[9];
  const float* bt1  = (const float*)d_in[10];
  const float* Wt2  = (const float*)d_in[11];
  const float* bt2  = (const float*)d_in[12];
  const float* Wih1 = (const float*)d_in[13];
  const float* Whh1 = (const float*)d_in[14];
  const float* bih1 = (const float*)d_in[15];
  const float* bhh1 = (const float*)d_in[16];
  const float* Wih2 = (const float*)d_in[17];
  const float* Whh2 = (const float*)d_in[18];
  const float* bih2 = (const float*)d_in[19];
  const float* bhh2 = (const float*)d_in[20];
  const float* Wl   = (const float*)d_in[21];
  const float* bl   = (const float*)d_in[22];
  const float* Wo   = (const float*)d_in[23];
  const float* bo   = (const float*)d_in[24];
  const float* Wso  = (const float*)d_in[25];
  const float* bso  = (const float*)d_in[26];

  float* out     = (float*)d_out;
  float* out_sfc = out + (size_t)BATCH * NLAY * 4;
  float* new_mem = out_sfc + (size_t)BATCH * 3;

  ushort_t* frag  = (ushort_t*)d_ws;                                   // 74752 ushorts
  ushort_t* r1buf = (ushort_t*)((char*)d_ws + 149504);                 // [B][60][64] bf16
  ushort_t* hLbuf = (ushort_t*)((char*)d_ws + 149504 + (size_t)BATCH * NLAY * NH * 2);

  wtranspose<<<292, 256, 0, stream>>>(Wih1, Whh1, Wih2, Whh2, Wl, frag);
  lstm_fused<<<BATCH / ROWS, TPB, 0, stream>>>(
      inputs_main, inputs_aux, rnn1_mem, Wi, bi, Ws1, bs1, Ws2, bs2,
      Wt1, bt1, Wt2, bt2, bih1, bhh1, bih2, bhh2, bl,
      frag, frag + 40960, frag + 73728, r1buf, hLbuf, new_mem);
  postpass<<<BATCH * NLAY / 256, 256, 0, stream>>>(new_mem, hLbuf, Wo, bo, Wso, bso, out, out_sfc);
}

// Round 4
// 263.520 us; speedup vs baseline: 5.4052x; 1.0621x over previous
//
#include <hip/hip_runtime.h>
#include <hip/hip_bf16.h>

#define BATCH 8192
#define NLAY  60
#define NH    64
#define ROWS  16
#define TPB   256
#define S1    168    // xh1 row stride (ushort): 84 dwords
#define S2    136    // xh2 row stride (ushort): 68 dwords

typedef unsigned short ushort_t;
typedef __attribute__((ext_vector_type(8))) short short8;
typedef __attribute__((ext_vector_type(4))) float f32x4;
typedef __attribute__((ext_vector_type(4))) float f4v;

__device__ __forceinline__ float rcp_(float x) { return __builtin_amdgcn_rcpf(x); }
__device__ __forceinline__ float sigm_(float x) { return rcp_(1.0f + __expf(-x)); }
__device__ __forceinline__ float tanh_(float x) { return 1.0f - 2.0f * rcp_(__expf(2.0f * x) + 1.0f); }
__device__ __forceinline__ ushort_t f2bu(float f) {       // scalar fp32->bf16 RNE
  unsigned u = __float_as_uint(f);
  return (ushort_t)((u + 0x7FFFu + ((u >> 16) & 1u)) >> 16);
}
__device__ __forceinline__ unsigned pkbf(float a, float b) {  // packs 2 bf16 in 1 dword
  union { __hip_bfloat162 h; unsigned u; } c;
  c.h = __float22bfloat162_rn(make_float2(a, b));
  return c.u;
}
__device__ __forceinline__ f32x4 mfma16(short8 a, short8 b, f32x4 c) {
  return __builtin_amdgcn_mfma_f32_16x16x32_bf16(a, b, c, 0, 0, 0);
}

// ---- Pre-pass: pack all matmul weights into MFMA B-fragment order (bf16) ----
// B-frag 16x16x32: lane holds B[k=(lane>>4)*8+j][n=lane&15], j=0..7 contiguous.
// Layout in frag[]: W1f [w][g][ks5][512] @0 ; W2f [w][g][ks4][512] @40960 ;
// WlF [ks2][512] @73728 ; WcF (Wo@Wl composed, cols 0..3) @74752 ;
// WsF (Wso, cols 0..2) @75776.  Total 76800 ushorts.
__global__ void wtranspose(const float* __restrict__ Wih1, const float* __restrict__ Whh1,
                           const float* __restrict__ Wih2, const float* __restrict__ Whh2,
                           const float* __restrict__ Wl,   const float* __restrict__ Wo,
                           const float* __restrict__ Wso,  ushort_t* __restrict__ frag) {
  int e = blockIdx.x * 256 + threadIdx.x;
  float v;
  if (e < 40960) {
    int j = e & 7, lx = (e >> 3) & 63, rest = e >> 9;
    int ks = rest % 5, gw = rest / 5;
    int g = gw & 3, wv = gw >> 2;
    int uu = wv * 16 + (lx & 15);
    int k = ks * 32 + (lx >> 4) * 8 + j;
    int row = g * 64 + uu;
    v = (k < 80) ? Wih1[row * 80 + k] : (k < 144 ? Whh1[row * 64 + (k - 80)] : 0.0f);
  } else if (e < 73728) {
    int e2 = e - 40960;
    int j = e2 & 7, lx = (e2 >> 3) & 63, rest = e2 >> 9;
    int ks = rest & 3, g = (rest >> 2) & 3, wv = rest >> 4;
    int uu = wv * 16 + (lx & 15);
    int k = ks * 32 + (lx >> 4) * 8 + j;
    int row = g * 64 + uu;
    v = (k < 64) ? Wih2[row * 64 + k] : Whh2[row * 64 + (k - 64)];
  } else if (e < 74752) {
    int e3 = e - 73728;
    int j = e3 & 7, lx = (e3 >> 3) & 63, ks = e3 >> 9;
    int n = lx & 15, k = ks * 32 + (lx >> 4) * 8 + j;
    v = Wl[n * 64 + k];
  } else if (e < 75776) {
    int e4 = e - 74752;
    int j = e4 & 7, lx = (e4 >> 3) & 63, ks = e4 >> 9;
    int n = lx & 15, k = ks * 32 + (lx >> 4) * 8 + j;
    v = 0.0f;
    if (n < 4) {
#pragma unroll
      for (int m = 0; m < 16; ++m) v += Wo[n * 16 + m] * Wl[m * 64 + k];
    }
  } else {
    int e5 = e - 75776;
    int j = e5 & 7, lx = (e5 >> 3) & 63, ks = e5 >> 9;
    int n = lx & 15, k = ks * 32 + (lx >> 4) * 8 + j;
    v = (n < 3) ? Wso[n * 64 + k] : 0.0f;
  }
  frag[e] = f2bu(v);
}

// ---- Fully-fused LSTM: 512 blocks x 256 thr, 16 batch rows/block, 1 barrier/step ----
__global__ __launch_bounds__(TPB, 2)
void lstm_fused(const float* __restrict__ inputs_main, const float* __restrict__ inputs_aux,
                const float* __restrict__ rnn1_mem,
                const float* __restrict__ Wi,  const float* __restrict__ bi,
                const float* __restrict__ Ws1, const float* __restrict__ bs1,
                const float* __restrict__ Ws2, const float* __restrict__ bs2,
                const float* __restrict__ Wt1, const float* __restrict__ bt1,
                const float* __restrict__ Wt2, const float* __restrict__ bt2,
                const float* __restrict__ bih1, const float* __restrict__ bhh1,
                const float* __restrict__ bih2, const float* __restrict__ bhh2,
                const float* __restrict__ bl,  const float* __restrict__ Wo,
                const float* __restrict__ bo,  const float* __restrict__ bso,
                const ushort_t* __restrict__ frag,
                ushort_t* __restrict__ r1buf,
                float* __restrict__ out, float* __restrict__ out_sfc,
                float* __restrict__ new_mem) {
  const ushort_t* W1f = frag;
  const ushort_t* W2f = frag + 40960;
  const ushort_t* WlF = frag + 73728;
  const ushort_t* WcF = frag + 74752;
  const ushort_t* WsF = frag + 75776;

  __shared__ __align__(16) ushort_t xh1[2][16 * S1];  // cols: xcat 0..79 | h1 80..143 | zero 144..159
  __shared__ __align__(16) ushort_t xh2[2][16 * S2];  // cols: r1 0..63 | h2 64..127
  __shared__ __align__(16) float inmS[16][244];

  const int tid = threadIdx.x;
  const int l  = tid & 63, w = tid >> 6;
  const int ln = l & 15,  lq = l >> 4;
  const int u  = w * 16 + ln;
  const int rowbase = lq * 4;
  const int b0 = blockIdx.x * ROWS;
  const int xr = tid >> 4, xm = tid & 15, xc0 = xm * 4;
  const int rr8 = tid >> 3, ch8 = tid & 7;

  // B1 fragments resident in VGPRs through LSTM1
  short8 B1f[4][5];
#pragma unroll
  for (int g = 0; g < 4; ++g)
#pragma unroll
    for (int ks = 0; ks < 5; ++ks)
      B1f[g][ks] = *(const short8*)(W1f + (((w * 4 + g) * 5 + ks) << 9) + (l << 3));

  f4v wif[4];
#pragma unroll
  for (int cc = 0; cc < 4; ++cc) wif[cc] = *(const f4v*)(Wi + (xc0 + cc) * 4);
  f4v bifv = *(const f4v*)(bi + xc0);

  float bg1[4];
#pragma unroll
  for (int g = 0; g < 4; ++g) bg1[g] = bih1[g * 64 + u] + bhh1[g * 64 + u];

  for (int e = tid; e < 16 * 240; e += TPB) {
    int r = e / 240, c = e - r * 240;
    inmS[r][c] = inputs_main[(size_t)(b0 + r) * 240 + c];
  }
  { // zero K-pad cols 144..159 in BOTH buffers (256 threads cover 16x16)
    int r = tid >> 4, c = 144 + (tid & 15);
    xh1[0][r * S1 + c] = 0; xh1[1][r * S1 + c] = 0;
  }
  __syncthreads();

  // ---- prologue: step-59 inputs + h1/c1 init into buffer 0 ----
  float c1[4];
  {
    float mv = rnn1_mem[(size_t)(b0 + xr) * 960 + 59 * 16 + xm];
    xh1[0][xr * S1 + 64 + xm] = f2bu(mv);
    f4v xin = *(const f4v*)&inmS[xr][59 * 4];
    float xp[4];
#pragma unroll
    for (int cc = 0; cc < 4; ++cc)
      xp[cc] = tanh_(bifv[cc] + wif[cc][0]*xin[0] + wif[cc][1]*xin[1] + wif[cc][2]*xin[2] + wif[cc][3]*xin[3]);
    *(uint2*)&xh1[0][xr * S1 + xc0] = make_uint2(pkbf(xp[0], xp[1]), pkbf(xp[2], xp[3]));

    float w10 = Ws1[u * 3 + 0], w11 = Ws1[u * 3 + 1], w12 = Ws1[u * 3 + 2], bb1 = bs1[u];
    float w20 = Ws2[u * 3 + 0], w21 = Ws2[u * 3 + 1], w22 = Ws2[u * 3 + 2], bb2 = bs2[u];
#pragma unroll
    for (int reg = 0; reg < 4; ++reg) {
      int row = rowbase + reg;
      const float* ax = inputs_aux + (size_t)(b0 + row) * 3;
      float a0 = ax[0], a1 = ax[1], a2 = ax[2];
      xh1[0][row * S1 + 80 + u] = f2bu(tanh_(w10 * a0 + w11 * a1 + w12 * a2 + bb1));
      c1[reg] = tanh_(w20 * a0 + w21 * a1 + w22 * a2 + bb2);
    }
  }
  __syncthreads();

  // ---- LSTM1: t = 59..0, double-buffered, ONE barrier per step ----
  int pb = 0;
  for (int t = NLAY - 1; t >= 0; --t) {
    const int nb = pb ^ 1;
    float mv = 0.0f; f4v xin = {};
    if (t > 0) {
      mv  = rnn1_mem[(size_t)(b0 + xr) * 960 + (t - 1) * 16 + xm];
      xin = *(const f4v*)&inmS[xr][(t - 1) * 4];
    }
    short8 af[5];
#pragma unroll
    for (int ks = 0; ks < 5; ++ks)
      af[ks] = *(const short8*)&xh1[pb][ln * S1 + ks * 32 + lq * 8];

    f32x4 acc[4];
#pragma unroll
    for (int g = 0; g < 4; ++g) acc[g] = (f32x4){bg1[g], bg1[g], bg1[g], bg1[g]};
#pragma unroll
    for (int ks = 0; ks < 5; ++ks)
#pragma unroll
      for (int g = 0; g < 4; ++g) acc[g] = mfma16(af[ks], B1f[g][ks], acc[g]);

    if (t > 0) {  // stage step-(t-1) xcat into next buffer (independent of MFMA)
      float xp[4];
#pragma unroll
      for (int cc = 0; cc < 4; ++cc)
        xp[cc] = tanh_(bifv[cc] + wif[cc][0]*xin[0] + wif[cc][1]*xin[1] + wif[cc][2]*xin[2] + wif[cc][3]*xin[3]);
      *(uint2*)&xh1[nb][xr * S1 + xc0] = make_uint2(pkbf(xp[0], xp[1]), pkbf(xp[2], xp[3]));
      xh1[nb][xr * S1 + 64 + xm] = f2bu(mv);
    }

    float h[4];
#pragma unroll
    for (int reg = 0; reg < 4; ++reg) {
      float ig = sigm_(acc[0][reg]);
      float fg = sigm_(acc[1][reg]);
      float gg = tanh_(acc[2][reg]);
      float og = sigm_(acc[3][reg]);
      float c  = fg * c1[reg] + ig * gg;
      c1[reg] = c;
      h[reg] = og * tanh_(c);
    }
    unsigned h01 = pkbf(h[0], h[1]), h23 = pkbf(h[2], h[3]);
    ushort_t hu[4] = {(ushort_t)h01, (ushort_t)(h01 >> 16), (ushort_t)h23, (ushort_t)(h23 >> 16)};
#pragma unroll
    for (int reg = 0; reg < 4; ++reg) {
      r1buf[((size_t)(b0 + rowbase + reg) * 60 + t) * 64 + u] = hu[reg];
      if (t > 0) xh1[nb][(rowbase + reg) * S1 + 80 + u] = hu[reg];
      else       xh2[0][(rowbase + reg) * S2 + u]       = hu[reg];  // r1(0) seeds LSTM2
    }
    __syncthreads();
    pb = nb;
  }

  // ---- LSTM2 setup: B2 frags, h2/c2 init into xh2[0], per-wave proj frags ----
  short8 B2f[4][4];
#pragma unroll
  for (int g = 0; g < 4; ++g)
#pragma unroll
    for (int ks = 0; ks < 4; ++ks)
      B2f[g][ks] = *(const short8*)(W2f + (((w * 4 + g) * 4 + ks) << 9) + (l << 3));
  float bg2[4];
#pragma unroll
  for (int g = 0; g < 4; ++g) bg2[g] = bih2[g * 64 + u] + bhh2[g * 64 + u];

  float c2[4];
  {
    float wt1u = Wt1[u], wt2u = Wt2[u], bt1u = bt1[u], bt2u = bt2[u];
#pragma unroll
    for (int reg = 0; reg < 4; ++reg) {
      int row = rowbase + reg;
      float toa = inputs_aux[(size_t)(b0 + row) * 3 + 1];
      xh2[0][row * S2 + 64 + u] = f2bu(toa * wt1u + bt1u);
      c2[reg] = toa * wt2u + bt2u;
    }
  }
  short8 PW0 = {}, PW1 = {};
  float pbias = 0.0f;
  if (w == 0) {          // lat -> new_mem
    PW0 = *(const short8*)(WlF + (l << 3));
    PW1 = *(const short8*)(WlF + 512 + (l << 3));
    pbias = bl[ln];
  } else if (w == 1) {   // composed out = h2 @ (Wo·Wl)^T + (bo + Wo·bl)
    PW0 = *(const short8*)(WcF + (l << 3));
    PW1 = *(const short8*)(WcF + 512 + (l << 3));
    if (ln < 4) {
      float a = bo[ln];
#pragma unroll
      for (int m = 0; m < 16; ++m) a += Wo[ln * 16 + m] * bl[m];
      pbias = a;
    }
  } else if (w == 2) {   // out_sfc tail
    PW0 = *(const short8*)(WsF + (l << 3));
    PW1 = *(const short8*)(WsF + 512 + (l << 3));
    pbias = (ln < 3) ? bso[ln] : 0.0f;
  }
  __syncthreads();

  // ---- LSTM2: t = 0..59, double-buffered, ONE barrier per step ----
  pb = 0;
  for (int t = 0; t < NLAY; ++t) {
    const int nb = pb ^ 1;
    short8 r1v = {};
    if (t < 59 && tid < 128)
      r1v = *(const short8*)(r1buf + ((size_t)(b0 + rr8) * 60 + (t + 1)) * 64 + ch8 * 8);
    short8 af2[4];
#pragma unroll
    for (int ks = 0; ks < 4; ++ks)
      af2[ks] = *(const short8*)&xh2[pb][ln * S2 + ks * 32 + lq * 8];

    f32x4 acc[4];
#pragma unroll
    for (int g = 0; g < 4; ++g) acc[g] = (f32x4){bg2[g], bg2[g], bg2[g], bg2[g]};
#pragma unroll
    for (int ks = 0; ks < 4; ++ks)
#pragma unroll
      for (int g = 0; g < 4; ++g) acc[g] = mfma16(af2[ks], B2f[g][ks], acc[g]);

    if (t > 0 && w < 2) {  // projections for step t-1 (h2(t-1) lives in xh2[pb])
      short8 aL0 = *(const short8*)&xh2[pb][ln * S2 + 64 + lq * 8];
      short8 aL1 = *(const short8*)&xh2[pb][ln * S2 + 96 + lq * 8];
      f32x4 ap = (f32x4){pbias, pbias, pbias, pbias};
      ap = mfma16(aL0, PW0, ap);
      ap = mfma16(aL1, PW1, ap);
      if (w == 0) {
#pragma unroll
        for (int reg = 0; reg < 4; ++reg)
          new_mem[((size_t)(b0 + rowbase + reg) * 60 + (t - 1)) * 16 + ln] = ap[reg];
      } else if (ln < 4) {
#pragma unroll
        for (int reg = 0; reg < 4; ++reg)
          out[((size_t)(b0 + rowbase + reg) * 60 + (t - 1)) * 4 + ln] = ap[reg];
      }
    }

    float h[4];
#pragma unroll
    for (int reg = 0; reg < 4; ++reg) {
      float ig = sigm_(acc[0][reg]);
      float fg = sigm_(acc[1][reg]);
      float gg = tanh_(acc[2][reg]);
      float og = sigm_(acc[3][reg]);
      float c  = fg * c2[reg] + ig * gg;
      c2[reg] = c;
      h[reg] = og * tanh_(c);
    }
    unsigned h01 = pkbf(h[0], h[1]), h23 = pkbf(h[2], h[3]);
    ushort_t hu[4] = {(ushort_t)h01, (ushort_t)(h01 >> 16), (ushort_t)h23, (ushort_t)(h23 >> 16)};
#pragma unroll
    for (int reg = 0; reg < 4; ++reg)
      xh2[nb][(rowbase + reg) * S2 + 64 + u] = hu[reg];
    if (t < 59 && tid < 128)
      *(short8*)&xh2[nb][rr8 * S2 + ch8 * 8] = r1v;
    __syncthreads();
    pb = nb;
  }

  // ---- tail: projections for t=59 + out_sfc (h2(59) is in xh2[0]) ----
  if (w < 3) {
    short8 aL0 = *(const short8*)&xh2[0][ln * S2 + 64 + lq * 8];
    short8 aL1 = *(const short8*)&xh2[0][ln * S2 + 96 + lq * 8];
    f32x4 ap = (f32x4){pbias, pbias, pbias, pbias};
    ap = mfma16(aL0, PW0, ap);
    ap = mfma16(aL1, PW1, ap);
    if (w == 0) {
#pragma unroll
      for (int reg = 0; reg < 4; ++reg)
        new_mem[((size_t)(b0 + rowbase + reg) * 60 + 59) * 16 + ln] = ap[reg];
    } else if (w == 1) {
      if (ln < 4) {
#pragma unroll
        for (int reg = 0; reg < 4; ++reg)
          out[((size_t)(b0 + rowbase + reg) * 60 + 59) * 4 + ln] = ap[reg];
      }
    } else {
      if (ln < 3) {
#pragma unroll
        for (int reg = 0; reg < 4; ++reg)
          out_sfc[(size_t)(b0 + rowbase + reg) * 3 + ln] = ap[reg];
      }
    }
  }
}

extern "C" void kernel_launch(void* const* d_in, const int* in_sizes, int n_in,
                              void* d_out, int out_size, void* d_ws, size_t ws_size,
                              hipStream_t stream) {
  (void)in_sizes; (void)n_in; (void)out_size; (void)ws_size;
  const float* inputs_main = (const float*)d_in[0];
  const float* inputs_aux  = (const float*)d_in[1];
  const float* rnn1_mem    = (const float*)d_in[2];
  const float* Wi   = (const float*)d_in[3];
  const float* bi   = (const float*)d_in[4];
  const float* Ws1  = (const float*)d_in[5];
  const float* bs1  = (const float*)d_in[6];
  const float* Ws2  = (const float*)d_in[7];
  const float* bs2  = (const float*)d_in[8];
  const float* Wt1  = (const float*)d_in[9];
  const float* bt1  = (const float*)d_in[10];
  const float* Wt2  = (const float*)d_in[11];
  const float* bt2  = (const float*)d_in[12];
  const float* Wih1 = (const float*)d_in[13];
  const float* Whh1 = (const float*)d_in[14];
  const float* bih1 = (const float*)d_in[15];
  const float* bhh1 = (const float*)d_in[16];
  const float* Wih2 = (const float*)d_in[17];
  const float* Whh2 = (const float*)d_in[18];
  const float* bih2 = (const float*)d_in[19];
  const float* bhh2 = (const float*)d_in[20];
  const float* Wl   = (const float*)d_in[21];
  const float* bl   = (const float*)d_in[22];
  const float* Wo   = (const float*)d_in[23];
  const float* bo   = (const float*)d_in[24];
  const float* Wso  = (const float*)d_in[25];
  const float* bso  = (const float*)d_in[26];

  float* out     = (float*)d_out;
  float* out_sfc = out + (size_t)BATCH * NLAY * 4;
  float* new_mem = out_sfc + (size_t)BATCH * 3;

  ushort_t* frag  = (ushort_t*)d_ws;                          // 76800 ushorts = 153600 B
  ushort_t* r1buf = (ushort_t*)((char*)d_ws + 153600);        // [B][60][64] bf16, 63 MB

  wtranspose<<<300, 256, 0, stream>>>(Wih1, Whh1, Wih2, Whh2, Wl, Wo, Wso, frag);
  lstm_fused<<<BATCH / ROWS, TPB, 0, stream>>>(
      inputs_main, inputs_aux, rnn1_mem, Wi, bi, Ws1, bs1, Ws2, bs2,
      Wt1, bt1, Wt2, bt2, bih1, bhh1, bih2, bhh2, bl, Wo, bo, bso,
      frag, r1buf, out, out_sfc, new_mem);
}